// Round 2
// baseline (1100.303 us; speedup 1.0000x reference)
//
#include <hip/hip_runtime.h>

// DigitCapsules dynamic routing, fused one-block-per-batch + W pre-transpose.
// B=256, C=10, I=1152, DI=8, DO=16, 3 routing iterations.
//
// Round-2 changes vs round-1:
//  - Pre-pass transposes W (5.9 MB) into ws as Wt[c][q][i] float4 (q in [0,32)
//    indexes the 16B chunks of one capsule's 512B weight block) so routing
//    loads are lane-coalesced (lane stride 16B, was 512B = 64 lines/load).
//  - Block 1024 threads (16 waves/CU, was 4): thread t owns i=t and, for
//    t<128, i=t+1024. Occupancy 12% -> ~50%.
//  - Falls back to direct (uncoalesced) W reads if ws_size < 5.9 MB.

#define NBATCH 256
#define NCLS   10
#define NCAPS  1152
#define KDI    8
#define KDO    16
#define NIT    3
#define NQ     32            // float4 chunks per (c,i) weight block (128 floats)
#define TPB    1024
#define NWAVE  (TPB / 64)

__global__ __launch_bounds__(256)
void transpose_W(const float4* __restrict__ W4, float4* __restrict__ Wt4) {
    int tid = blockIdx.x * blockDim.x + threadIdx.x;      // over C*NQ*I
    if (tid >= NCLS * NQ * NCAPS) return;
    int i = tid % NCAPS;
    int r = tid / NCAPS;                                  // c*NQ + q
    int q = r % NQ;
    int c = r / NQ;
    // write coalesced (i fastest); read is strided but one-shot / L2-absorbed
    Wt4[tid] = W4[(size_t)(c * NCAPS + i) * NQ + q];
}

template <bool TR>
__global__ __launch_bounds__(TPB, 4)
void caps_routing(const float4* __restrict__ Wv,  // TR: [C][NQ][I], else [C][I][NQ]
                  const float* __restrict__ x,    // [B, I, DI]
                  float* __restrict__ out)        // [B, C, 1, DO]
{
    const int b    = blockIdx.x;
    const int t    = threadIdx.x;
    const int lane = t & 63;
    const int wave = t >> 6;

    __shared__ float v_prev[NCLS * KDO];          // v from previous iteration
    __shared__ float red[NCLS * NWAVE * KDO];     // per-wave partial s

    // ---- x[b, i, :] for my i's in registers (coalesced float4) ----
    float4 xr[2][2];
    const float4* x4 = reinterpret_cast<const float4*>(x) + (size_t)b * NCAPS * 2;
    #pragma unroll
    for (int j = 0; j < 2; ++j) {
        int ii = t + TPB * j;
        if (ii < NCAPS) {
            xr[j][0] = x4[2 * ii];
            xr[j][1] = x4[2 * ii + 1];
        }
    }

    // ---- routing logits, thread-local ----
    float blog[2][NCLS];
    #pragma unroll
    for (int j = 0; j < 2; ++j)
        #pragma unroll
        for (int c = 0; c < NCLS; ++c)
            blog[j][c] = 0.f;

    for (int it = 0; it < NIT; ++it) {
        // ---- Phase A: blog[i][c] += <u_hat[c,i,:], v_prev[c,:]> ----
        if (it > 0) {
            for (int c = 0; c < NCLS; ++c) {
                float vp[KDO];
                #pragma unroll
                for (int d = 0; d < KDO; ++d)
                    vp[d] = v_prev[c * KDO + d];          // LDS broadcast

                #pragma unroll
                for (int j = 0; j < 2; ++j) {
                    int ii = t + TPB * j;
                    if (ii < NCAPS) {
                        float a = 0.f;
                        #pragma unroll
                        for (int q = 0; q < NQ; ++q) {
                            size_t addr = TR ? ((size_t)(c * NQ + q) * NCAPS + ii)
                                             : ((size_t)(c * NCAPS + ii) * NQ + q);
                            float4 w = Wv[addr];
                            float4 p = (q & 1) ? xr[j][1] : xr[j][0];
                            float dw = w.x * p.x + w.y * p.y + w.z * p.z + w.w * p.w;
                            a += dw * vp[q >> 1];
                        }
                        blog[j][c] += a;
                    }
                }
            }
        }

        // ---- Phase B: softmax over classes (thread-local) ----
        float sm[2], sid[2];
        #pragma unroll
        for (int j = 0; j < 2; ++j) {
            int ii = t + TPB * j;
            if (ii < NCAPS) {
                float m = blog[j][0];
                #pragma unroll
                for (int c = 1; c < NCLS; ++c) m = fmaxf(m, blog[j][c]);
                float den = 0.f;
                #pragma unroll
                for (int c = 0; c < NCLS; ++c) den += __expf(blog[j][c] - m);
                sm[j]  = m;
                sid[j] = 1.f / den;
            }
        }

        // ---- Phase C: s[c,:] = sum_i softmax_c(blog) * u_hat[c,i,:] ----
        for (int c = 0; c < NCLS; ++c) {
            float acc[KDO];
            #pragma unroll
            for (int d = 0; d < KDO; ++d) acc[d] = 0.f;

            #pragma unroll
            for (int j = 0; j < 2; ++j) {
                int ii = t + TPB * j;
                if (ii < NCAPS) {
                    float wgt = __expf(blog[j][c] - sm[j]) * sid[j];
                    #pragma unroll
                    for (int q = 0; q < NQ; ++q) {
                        size_t addr = TR ? ((size_t)(c * NQ + q) * NCAPS + ii)
                                         : ((size_t)(c * NCAPS + ii) * NQ + q);
                        float4 w = Wv[addr];
                        float4 p = (q & 1) ? xr[j][1] : xr[j][0];
                        float dw = w.x * p.x + w.y * p.y + w.z * p.z + w.w * p.w;
                        acc[q >> 1] += wgt * dw;
                    }
                }
            }

            // block-reduce acc[d]: wave shuffle, then per-wave partial to LDS
            #pragma unroll
            for (int d = 0; d < KDO; ++d) {
                float v = acc[d];
                v += __shfl_xor(v, 32, 64);
                v += __shfl_xor(v, 16, 64);
                v += __shfl_xor(v,  8, 64);
                v += __shfl_xor(v,  4, 64);
                v += __shfl_xor(v,  2, 64);
                v += __shfl_xor(v,  1, 64);
                if (lane == 0) red[(c * NWAVE + wave) * KDO + d] = v;
            }
        }
        __syncthreads();

        // ---- squash + v broadcast: threads 0..159 (c = t/16, d = t%16) ----
        if (t < NCLS * KDO) {
            int c = t >> 4;
            int d = t & 15;
            float s = 0.f;
            #pragma unroll
            for (int w = 0; w < NWAVE; ++w)
                s += red[(c * NWAVE + w) * KDO + d];
            float nsq = s * s;
            nsq += __shfl_xor(nsq, 8, 16);
            nsq += __shfl_xor(nsq, 4, 16);
            nsq += __shfl_xor(nsq, 2, 16);
            nsq += __shfl_xor(nsq, 1, 16);
            float scale = sqrtf(nsq) / (1.f + nsq);       // (nsq/(1+nsq))/sqrt(nsq)
            float vv = s * scale;
            v_prev[t] = vv;
            if (it == NIT - 1)
                out[(size_t)b * NCLS * KDO + t] = vv;
        }
        __syncthreads();
    }
}

extern "C" void kernel_launch(void* const* d_in, const int* in_sizes, int n_in,
                              void* d_out, int out_size, void* d_ws, size_t ws_size,
                              hipStream_t stream) {
    const float* x = (const float*)d_in[0];               // [256, 1152, 8] fp32
    const float4* W4 = (const float4*)d_in[1];            // [10, 1152, 1, 16, 8] fp32
    float* out = (float*)d_out;                           // [256, 10, 1, 16] fp32
    (void)in_sizes; (void)n_in; (void)out_size;

    const size_t wt_bytes = (size_t)NCLS * NQ * NCAPS * sizeof(float4);  // 5.9 MB
    if (ws_size >= wt_bytes) {
        float4* Wt = (float4*)d_ws;
        int total = NCLS * NQ * NCAPS;
        transpose_W<<<dim3((total + 255) / 256), dim3(256), 0, stream>>>(W4, Wt);
        caps_routing<true><<<dim3(NBATCH), dim3(TPB), 0, stream>>>(Wt, x, out);
    } else {
        caps_routing<false><<<dim3(NBATCH), dim3(TPB), 0, stream>>>(W4, x, out);
    }
}

// Round 3
// 760.526 us; speedup vs baseline: 1.4468x; 1.4468x over previous
//
#include <hip/hip_runtime.h>
#include <hip/hip_bf16.h>

// DigitCapsules dynamic routing. Round-3 design:
//  - One block per batch element, 512 threads (8 waves). launch_bounds(512,2)
//    -> 256-VGPR cap. Round-2's 1024-thread block capped VGPRs at 128 and the
//    compiler spilled everything to scratch (949 MB WRITE_SIZE) -- never again.
//  - Pre-pass packs W (fp32, 5.9 MB) into bf16 layout Wt[c][d][i] as uint4
//    (8 bf16 = the k-row of one (c,i,d)): lane-coalesced (16 B stride on i),
//    half the L2 bytes, half the load instructions of fp32.
//  - Thread t owns capsules ii = t + 512*j (j=0,1, plus j=2 for t<128).
//  - blog thread-local -> softmax over classes needs no communication.
//  - s block-reduced via wave shuffles + LDS; squash by threads 0..159.
//  - Fallback to direct fp32 W reads if ws too small for the 2.95 MB pack.

#define NCLS   10
#define NCAPS  1152
#define KDO    16
#define NIT    3
#define TPB    512
#define NJ     3
#define NWAVE  (TPB / 64)

static __device__ __forceinline__ unsigned short f2bf(float f) {
    __hip_bfloat16 h = __float2bfloat16(f);
    return *reinterpret_cast<unsigned short*>(&h);
}

// Wt[c][d][i] : uint4 holding bf16 W[c,i,0,d,k] for k=0..7 (k even -> low half)
__global__ __launch_bounds__(256)
void pack_W_bf16(const float4* __restrict__ W4, uint4* __restrict__ Wt) {
    int tid = blockIdx.x * blockDim.x + threadIdx.x;   // (c*NCAPS+i)*KDO + d
    if (tid >= NCLS * NCAPS * KDO) return;
    int d = tid & 15;
    int rest = tid >> 4;
    int i = rest % NCAPS;
    int c = rest / NCAPS;
    float4 a = W4[2 * tid];        // coalesced reads (d fastest, 32 B stride)
    float4 b = W4[2 * tid + 1];
    uint4 o;
    o.x = (unsigned)f2bf(a.x) | ((unsigned)f2bf(a.y) << 16);
    o.y = (unsigned)f2bf(a.z) | ((unsigned)f2bf(a.w) << 16);
    o.z = (unsigned)f2bf(b.x) | ((unsigned)f2bf(b.y) << 16);
    o.w = (unsigned)f2bf(b.z) | ((unsigned)f2bf(b.w) << 16);
    Wt[(size_t)(c * KDO + d) * NCAPS + i] = o;         // scattered writes, one-shot
}

static __device__ __forceinline__ float dot_bf8(uint4 r, const float4& x0, const float4& x1) {
    float e0 = __uint_as_float(r.x << 16);
    float e1 = __uint_as_float(r.x & 0xffff0000u);
    float e2 = __uint_as_float(r.y << 16);
    float e3 = __uint_as_float(r.y & 0xffff0000u);
    float e4 = __uint_as_float(r.z << 16);
    float e5 = __uint_as_float(r.z & 0xffff0000u);
    float e6 = __uint_as_float(r.w << 16);
    float e7 = __uint_as_float(r.w & 0xffff0000u);
    return e0 * x0.x + e1 * x0.y + e2 * x0.z + e3 * x0.w
         + e4 * x1.x + e5 * x1.y + e6 * x1.z + e7 * x1.w;
}

static __device__ __forceinline__ float dot_f8(const float4* W4, size_t row2,
                                               const float4& x0, const float4& x1) {
    float4 w0 = W4[row2];
    float4 w1 = W4[row2 + 1];
    return w0.x * x0.x + w0.y * x0.y + w0.z * x0.z + w0.w * x0.w
         + w1.x * x1.x + w1.y * x1.y + w1.z * x1.z + w1.w * x1.w;
}

template <bool TR>
__global__ __launch_bounds__(TPB, 2)
void caps_routing(const uint4* __restrict__ Wt,   // TR path: [C][KDO][I] bf16x8
                  const float4* __restrict__ W4,  // fallback: [C][I][KDO][8] fp32
                  const float* __restrict__ x,    // [B, I, 8]
                  float* __restrict__ out)        // [B, C, 1, KDO]
{
    const int b    = blockIdx.x;
    const int t    = threadIdx.x;
    const int lane = t & 63;
    const int wave = t >> 6;

    __shared__ float v_prev[NCLS * KDO];             // 640 B
    __shared__ float red[NCLS * NWAVE * KDO];        // 5120 B

    // ---- x[b, ii, :] in registers ----
    float4 xr[NJ][2];
    const float4* x4 = reinterpret_cast<const float4*>(x) + (size_t)b * NCAPS * 2;
    #pragma unroll
    for (int j = 0; j < NJ; ++j) {
        int ii = t + TPB * j;
        if (ii < NCAPS) {
            xr[j][0] = x4[2 * ii];
            xr[j][1] = x4[2 * ii + 1];
        }
    }

    float blog[NJ][NCLS];
    #pragma unroll
    for (int j = 0; j < NJ; ++j)
        #pragma unroll
        for (int c = 0; c < NCLS; ++c)
            blog[j][c] = 0.f;

    for (int it = 0; it < NIT; ++it) {
        // ---- Phase A: blog[ii][c] += <u_hat[c,ii,:], v_prev[c,:]> ----
        if (it > 0) {
            for (int c = 0; c < NCLS; ++c) {
                float vp[KDO];
                #pragma unroll
                for (int d = 0; d < KDO; ++d)
                    vp[d] = v_prev[c * KDO + d];
                #pragma unroll
                for (int j = 0; j < NJ; ++j) {
                    int ii = t + TPB * j;
                    if (ii < NCAPS) {
                        float a = 0.f;
                        #pragma unroll
                        for (int d = 0; d < KDO; ++d) {
                            float u = TR ? dot_bf8(Wt[(size_t)(c * KDO + d) * NCAPS + ii],
                                                   xr[j][0], xr[j][1])
                                         : dot_f8(W4, ((size_t)(c * NCAPS + ii) * KDO + d) * 2,
                                                  xr[j][0], xr[j][1]);
                            a += u * vp[d];
                        }
                        blog[j][c] += a;
                    }
                }
            }
        }

        // ---- Phase B: softmax over classes (thread-local) ----
        float sm[NJ], sid[NJ];
        #pragma unroll
        for (int j = 0; j < NJ; ++j) {
            int ii = t + TPB * j;
            if (ii < NCAPS) {
                float m = blog[j][0];
                #pragma unroll
                for (int c = 1; c < NCLS; ++c) m = fmaxf(m, blog[j][c]);
                float den = 0.f;
                #pragma unroll
                for (int c = 0; c < NCLS; ++c) den += __expf(blog[j][c] - m);
                sm[j]  = m;
                sid[j] = 1.f / den;
            }
        }

        // ---- Phase C: s[c,:] = sum_ii softmax_c(blog) * u_hat[c,ii,:] ----
        for (int c = 0; c < NCLS; ++c) {
            float acc[KDO];
            #pragma unroll
            for (int d = 0; d < KDO; ++d) acc[d] = 0.f;

            #pragma unroll
            for (int j = 0; j < NJ; ++j) {
                int ii = t + TPB * j;
                if (ii < NCAPS) {
                    float wgt = __expf(blog[j][c] - sm[j]) * sid[j];
                    #pragma unroll
                    for (int d = 0; d < KDO; ++d) {
                        float u = TR ? dot_bf8(Wt[(size_t)(c * KDO + d) * NCAPS + ii],
                                               xr[j][0], xr[j][1])
                                     : dot_f8(W4, ((size_t)(c * NCAPS + ii) * KDO + d) * 2,
                                              xr[j][0], xr[j][1]);
                        acc[d] += wgt * u;
                    }
                }
            }

            #pragma unroll
            for (int d = 0; d < KDO; ++d) {
                float v = acc[d];
                v += __shfl_xor(v, 32, 64);
                v += __shfl_xor(v, 16, 64);
                v += __shfl_xor(v,  8, 64);
                v += __shfl_xor(v,  4, 64);
                v += __shfl_xor(v,  2, 64);
                v += __shfl_xor(v,  1, 64);
                if (lane == 0) red[(c * NWAVE + wave) * KDO + d] = v;
            }
        }
        __syncthreads();

        // ---- squash + broadcast: threads 0..159 (c = t/16, d = t%16) ----
        if (t < NCLS * KDO) {
            int c = t >> 4;
            int d = t & 15;
            float s = 0.f;
            #pragma unroll
            for (int w = 0; w < NWAVE; ++w)
                s += red[(c * NWAVE + w) * KDO + d];
            float nsq = s * s;
            nsq += __shfl_xor(nsq, 8, 16);
            nsq += __shfl_xor(nsq, 4, 16);
            nsq += __shfl_xor(nsq, 2, 16);
            nsq += __shfl_xor(nsq, 1, 16);
            float scale = sqrtf(nsq) / (1.f + nsq);      // (nsq/(1+nsq))/sqrt(nsq)
            float vv = s * scale;
            v_prev[t] = vv;
            if (it == NIT - 1)
                out[(size_t)b * NCLS * KDO + t] = vv;
        }
        __syncthreads();
    }
}

extern "C" void kernel_launch(void* const* d_in, const int* in_sizes, int n_in,
                              void* d_out, int out_size, void* d_ws, size_t ws_size,
                              hipStream_t stream) {
    const float* x = (const float*)d_in[0];              // [256, 1152, 8] fp32
    const float4* W4 = (const float4*)d_in[1];           // [10, 1152, 1, 16, 8] fp32
    float* out = (float*)d_out;                          // [256, 10, 1, 16] fp32
    (void)in_sizes; (void)n_in; (void)out_size;

    const int B = 256;
    const size_t wt_bytes = (size_t)NCLS * KDO * NCAPS * sizeof(uint4);  // 2.95 MB
    if (ws_size >= wt_bytes) {
        uint4* Wt = (uint4*)d_ws;
        int total = NCLS * NCAPS * KDO;
        pack_W_bf16<<<dim3((total + 255) / 256), dim3(256), 0, stream>>>(W4, Wt);
        caps_routing<true><<<dim3(B), dim3(TPB), 0, stream>>>(Wt, W4, x, out);
    } else {
        caps_routing<false><<<dim3(B), dim3(TPB), 0, stream>>>(nullptr, W4, x, out);
    }
}